// Round 7
// baseline (137.491 us; speedup 1.0000x reference)
//
#include <hip/hip_runtime.h>

// PatchDivider R6: scatter-direction permutation (R5 with the K3 grid bug
// fixed: 16384 blocks, not 64).
//
//  K1: inv[orders[i]] = i         (coalesced read; random 4B scatter into
//                                  16.8MB buffer ~2MB/XCD -> L2-resident)
//  K2: raw[inv[s]] = pts[s]       (coalesced reads; random 12B scatter,
//                                  each address written exactly once)
//  K3: wave-per-patch mean/subtract on contiguous raw (R0's epilogue).
//
// No atomics, no LDS, no sort. Deterministic. ws: inv 16.8MB + raw 50.3MB.

#define PD_TOTAL  (32 * 131072)            // 4,194,304 points
#define PD_PATCH  64
#define PD_NPATCH (PD_TOTAL / PD_PATCH)    // 65,536

#define WS_INV_OFF 0
#define WS_RAW_OFF ((size_t)PD_TOTAL * 4)                  // 16,777,216
#define WS_NEEDED  (WS_RAW_OFF + (size_t)PD_TOTAL * 12)    // 67,108,864

struct pt3 { float x, y, z; };

// ---------------- K1: build inverse permutation ----------------
__global__ __launch_bounds__(256) void pd_inv(
    const int* __restrict__ orders, int* __restrict__ inv)
{
    const int i0 = (blockIdx.x * 256 + threadIdx.x) * 4;
    const int4 s = *(const int4*)(orders + i0);
    inv[s.x] = i0;
    inv[s.y] = i0 + 1;
    inv[s.z] = i0 + 2;
    inv[s.w] = i0 + 3;
}

// ---------------- K2: streamed scatter pts -> raw[dst] ----------------
__global__ __launch_bounds__(256) void pd_scatter(
    const float* __restrict__ pts, const int* __restrict__ inv,
    float* __restrict__ raw)
{
    const int base = blockIdx.x * 1024;
    #pragma unroll
    for (int k = 0; k < 4; ++k) {
        const int s = base + threadIdx.x + k * 256;
        const pt3 q = *(const pt3*)(pts + (size_t)s * 3);   // coalesced
        const int d = inv[s];                               // coalesced
        *(pt3*)(raw + (size_t)d * 3) = q;                   // random 12B store
    }
}

// ---------------- K3: per-patch mean + subtract (contiguous) ----------------
// one wave per patch: 65536 waves = 4,194,304 threads = 16384 blocks of 256
__global__ __launch_bounds__(256) void pd_finish(
    const float* __restrict__ raw, float* __restrict__ out)
{
    const int gtid = blockIdx.x * blockDim.x + threadIdx.x;
    const int wave = gtid >> 6;                 // patch id
    const int lane = threadIdx.x & 63;
    const size_t point = (size_t)wave * PD_PATCH + lane;

    const pt3 q = *(const pt3*)(raw + point * 3);   // coalesced 768B/wave

    float sx = q.x, sy = q.y, sz = q.z;
    #pragma unroll
    for (int off = 32; off >= 1; off >>= 1) {
        sx += __shfl_xor(sx, off, 64);
        sy += __shfl_xor(sy, off, 64);
        sz += __shfl_xor(sz, off, 64);
    }
    const float inv64 = 1.0f / (float)PD_PATCH;
    const float cx = sx * inv64, cy = sy * inv64, cz = sz * inv64;

    pt3 r = { q.x - cx, q.y - cy, q.z - cz };
    *(pt3*)(out + point * 3) = r;

    if (lane == 0) {
        pt3 c = { cx, cy, cz };
        *(pt3*)(out + (size_t)PD_TOTAL * 3 + (size_t)wave * 3) = c;
    }
}

// ---------------- fallback: R0 direct gather ----------------
__global__ __launch_bounds__(256) void pd_simple(
    const float* __restrict__ pts, const int* __restrict__ orders,
    float* __restrict__ out)
{
    const int gtid = blockIdx.x * blockDim.x + threadIdx.x;
    const int wave = gtid >> 6;
    const int lane = threadIdx.x & 63;
    const long long point = (long long)wave * PD_PATCH + lane;
    const int idx = orders[point];
    const pt3 q = *(const pt3*)(pts + (size_t)idx * 3);
    float sx = q.x, sy = q.y, sz = q.z;
    #pragma unroll
    for (int off = 32; off >= 1; off >>= 1) {
        sx += __shfl_xor(sx, off, 64);
        sy += __shfl_xor(sy, off, 64);
        sz += __shfl_xor(sz, off, 64);
    }
    const float inv64 = 1.0f / (float)PD_PATCH;
    const float cx = sx * inv64, cy = sy * inv64, cz = sz * inv64;
    pt3 r = { q.x - cx, q.y - cy, q.z - cz };
    *(pt3*)(out + point * 3) = r;
    if (lane == 0) {
        pt3 c = { cx, cy, cz };
        *(pt3*)(out + (size_t)PD_TOTAL * 3 + (size_t)wave * 3) = c;
    }
}

extern "C" void kernel_launch(void* const* d_in, const int* in_sizes, int n_in,
                              void* d_out, int out_size, void* d_ws, size_t ws_size,
                              hipStream_t stream) {
    const float* pts  = (const float*)d_in[0];
    const int* orders = (const int*)d_in[1];
    float* out        = (float*)d_out;

    if (ws_size < WS_NEEDED) {
        pd_simple<<<PD_TOTAL / 256, 256, 0, stream>>>(pts, orders, out);
        return;
    }

    int*   inv = (int*)((char*)d_ws + WS_INV_OFF);
    float* raw = (float*)((char*)d_ws + WS_RAW_OFF);

    pd_inv    <<<PD_TOTAL / 1024, 256, 0, stream>>>(orders, inv);
    pd_scatter<<<PD_TOTAL / 1024, 256, 0, stream>>>(pts, inv, raw);
    pd_finish <<<PD_TOTAL / 64 / 256 * 64, 256, 0, stream>>>(raw, out);  // 16384
}

// Round 8
// 91.189 us; speedup vs baseline: 1.5078x; 1.5078x over previous
//
#include <hip/hip_runtime.h>

// PatchDivider FINAL: fused wave-per-patch gather (R0 structure).
//
// Measured across 6 structural variants (direct gather / MLP-boosted gather /
// windowed sweep / block-sorted gather / atomic binning / inverse scatter),
// the 4.19M random line-granular accesses of this permutation cost 85-95us
// in EVERY direction (~3.5 TB/s random-64B L2-fill service rate; scatter
// direction is worse: 40B/pt sector writebacks at ~1.9 TB/s). This fused
// single-kernel gather does the permutation + mean + subtract + all
// streaming traffic in the same 92us the bare permutation costs -> at the
// random-access roofline.
//
// One 64-lane wave == one patch: lane i gathers point i, 6-step butterfly
// for the patch sum, coalesced centered writes, lane 0 writes the center.

#define PD_TOTAL  (32 * 131072)            // 4,194,304 points
#define PD_PATCH  64
#define PD_NPATCH (PD_TOTAL / PD_PATCH)    // 65,536

struct pt3 { float x, y, z; };

__global__ __launch_bounds__(256) void PatchDivider_57621281243393_kernel(
    const float* __restrict__ pts,
    const int* __restrict__ orders,
    float* __restrict__ out)
{
    const int gtid = blockIdx.x * blockDim.x + threadIdx.x;
    const int wave = gtid >> 6;           // patch index in [0, 65536)
    const int lane = threadIdx.x & 63;

    const long long point = (long long)wave * PD_PATCH + lane;
    const int idx = orders[point];        // coalesced 4B/lane

    const float* __restrict__ p = pts + (long long)idx * 3;
    const float x = p[0];
    const float y = p[1];
    const float z = p[2];

    // wave-wide sum across all 64 lanes (butterfly)
    float sx = x, sy = y, sz = z;
    #pragma unroll
    for (int off = 32; off >= 1; off >>= 1) {
        sx += __shfl_xor(sx, off, 64);
        sy += __shfl_xor(sy, off, 64);
        sz += __shfl_xor(sz, off, 64);
    }
    const float inv = 1.0f / (float)PD_PATCH;
    const float cx = sx * inv;
    const float cy = sy * inv;
    const float cz = sz * inv;

    // centered point -> patches output (wave writes contiguous 768B span)
    float* __restrict__ po = out + point * 3;
    po[0] = x - cx;
    po[1] = y - cy;
    po[2] = z - cz;

    // lane 0 writes the patch center after the patches block
    if (lane == 0) {
        float* __restrict__ co =
            out + (long long)PD_TOTAL * 3 + (long long)wave * 3;
        co[0] = cx;
        co[1] = cy;
        co[2] = cz;
    }
}

extern "C" void kernel_launch(void* const* d_in, const int* in_sizes, int n_in,
                              void* d_out, int out_size, void* d_ws, size_t ws_size,
                              hipStream_t stream) {
    const float* pts   = (const float*)d_in[0];
    const int* orders  = (const int*)d_in[1];
    float* out         = (float*)d_out;

    const int total_threads = PD_NPATCH * PD_PATCH;   // 4,194,304
    const int block = 256;
    const int grid = total_threads / block;           // 16,384

    PatchDivider_57621281243393_kernel<<<grid, block, 0, stream>>>(pts, orders, out);
}